// Round 1
// baseline (430.990 us; speedup 1.0000x reference)
//
#include <hip/hip_runtime.h>

// Sparsemax over rows: x is [16384, 4096] fp32, out same shape fp32.
// One block per row; each thread holds 16 elements in registers.
// tau found via candidate compaction (support \subseteq {x > rowmax-1})
// + Michelot fixed-point iteration on the tiny candidate list in LDS.

constexpr int COLS = 4096;
constexpr int TPB  = 256;   // 4 waves; 16 elements/thread
constexpr int CAP  = 1024;  // candidate capacity (expected ~14 for N(0,1) rows)

__global__ __launch_bounds__(TPB) void sparsemax_kernel(const float* __restrict__ x,
                                                        float* __restrict__ out) {
    const int row = blockIdx.x;
    const int tid = threadIdx.x;
    const float4* __restrict__ xr  = reinterpret_cast<const float4*>(x + (size_t)row * COLS);
    float4* __restrict__       orr = reinterpret_cast<float4*>(out + (size_t)row * COLS);

    // Coalesced: consecutive threads read consecutive float4s.
    float4 a = xr[tid], b = xr[tid + TPB], c = xr[tid + 2 * TPB], d = xr[tid + 3 * TPB];
    float v[16] = {a.x, a.y, a.z, a.w, b.x, b.y, b.z, b.w,
                   c.x, c.y, c.z, c.w, d.x, d.y, d.z, d.w};

    __shared__ float red[4];
    __shared__ float redc[4];
    __shared__ float cand[CAP];
    __shared__ int   ccount;
    __shared__ float tau_sh;

    // ---- block max reduction ----
    float mx = v[0];
    #pragma unroll
    for (int j = 1; j < 16; ++j) mx = fmaxf(mx, v[j]);
    #pragma unroll
    for (int m = 32; m; m >>= 1) mx = fmaxf(mx, __shfl_xor(mx, m, 64));
    if ((tid & 63) == 0) red[tid >> 6] = mx;
    if (tid == 0) ccount = 0;
    __syncthreads();
    const float rowmax = fmaxf(fmaxf(red[0], red[1]), fmaxf(red[2], red[3]));
    const float lb = rowmax - 1.0f;   // tau* >= rowmax - 1, support subset of {x > lb}

    // ---- compact candidates to LDS ----
    #pragma unroll
    for (int j = 0; j < 16; ++j) {
        if (v[j] > lb) {
            int idx = atomicAdd(&ccount, 1);
            if (idx < CAP) cand[idx] = v[j];
        }
    }
    __syncthreads();
    const int nc = ccount;  // block-uniform

    float tau;
    if (nc <= CAP) {
        // ---- Michelot fixed point, wave 0 only, shuffle reductions ----
        if (tid < 64) {
            float s = 0.f, cnt = 0.f;
            for (int j = tid; j < nc; j += 64) { s += cand[j]; cnt += 1.f; }
            #pragma unroll
            for (int m = 32; m; m >>= 1) { s += __shfl_xor(s, m, 64); cnt += __shfl_xor(cnt, m, 64); }
            float t = (s - 1.f) / cnt;       // tau_0 <= tau*, monotone increasing to tau*
            for (int it = 0; it < CAP + 2; ++it) {
                s = 0.f; cnt = 0.f;
                for (int j = tid; j < nc; j += 64) {
                    float cv = cand[j];
                    if (cv > t) { s += cv; cnt += 1.f; }
                }
                #pragma unroll
                for (int m = 32; m; m >>= 1) { s += __shfl_xor(s, m, 64); cnt += __shfl_xor(cnt, m, 64); }
                float nt = (s - 1.f) / cnt;  // cnt >= 1 always (rowmax > tau)
                if (nt == t) break;          // set stabilized -> exact
                t = nt;
            }
            if (tid == 0) tau_sh = t;
        }
        __syncthreads();
        tau = tau_sh;
    } else {
        // ---- fallback: block binary search over registers (pathological rows) ----
        float lo = lb, hi = rowmax;
        for (int it = 0; it < 40; ++it) {
            float mid = 0.5f * (lo + hi);
            float s = 0.f;
            #pragma unroll
            for (int j = 0; j < 16; ++j) s += fmaxf(v[j] - mid, 0.f);
            #pragma unroll
            for (int m = 32; m; m >>= 1) s += __shfl_xor(s, m, 64);
            if ((tid & 63) == 0) red[tid >> 6] = s;
            __syncthreads();
            s = red[0] + red[1] + red[2] + red[3];
            __syncthreads();
            if (s > 1.f) lo = mid; else hi = mid;
        }
        // exact final step from the lower bound
        float s = 0.f, cnt = 0.f;
        #pragma unroll
        for (int j = 0; j < 16; ++j) if (v[j] > lo) { s += v[j]; cnt += 1.f; }
        #pragma unroll
        for (int m = 32; m; m >>= 1) { s += __shfl_xor(s, m, 64); cnt += __shfl_xor(cnt, m, 64); }
        if ((tid & 63) == 0) { red[tid >> 6] = s; redc[tid >> 6] = cnt; }
        __syncthreads();
        s   = red[0] + red[1] + red[2] + red[3];
        cnt = redc[0] + redc[1] + redc[2] + redc[3];
        tau = (s - 1.f) / cnt;
    }

    // ---- epilogue: out = max(x - tau, 0), float4 stores ----
    float4 o0 = make_float4(fmaxf(v[0] - tau, 0.f),  fmaxf(v[1] - tau, 0.f),
                            fmaxf(v[2] - tau, 0.f),  fmaxf(v[3] - tau, 0.f));
    float4 o1 = make_float4(fmaxf(v[4] - tau, 0.f),  fmaxf(v[5] - tau, 0.f),
                            fmaxf(v[6] - tau, 0.f),  fmaxf(v[7] - tau, 0.f));
    float4 o2 = make_float4(fmaxf(v[8] - tau, 0.f),  fmaxf(v[9] - tau, 0.f),
                            fmaxf(v[10] - tau, 0.f), fmaxf(v[11] - tau, 0.f));
    float4 o3 = make_float4(fmaxf(v[12] - tau, 0.f), fmaxf(v[13] - tau, 0.f),
                            fmaxf(v[14] - tau, 0.f), fmaxf(v[15] - tau, 0.f));
    orr[tid]           = o0;
    orr[tid + TPB]     = o1;
    orr[tid + 2 * TPB] = o2;
    orr[tid + 3 * TPB] = o3;
}

extern "C" void kernel_launch(void* const* d_in, const int* in_sizes, int n_in,
                              void* d_out, int out_size, void* d_ws, size_t ws_size,
                              hipStream_t stream) {
    const float* x  = (const float*)d_in[0];
    float*       o  = (float*)d_out;
    const int rows  = in_sizes[0] / COLS;   // 16384
    sparsemax_kernel<<<rows, TPB, 0, stream>>>(x, o);
}